// Round 4
// baseline (304.107 us; speedup 1.0000x reference)
//
#include <hip/hip_runtime.h>
#include <hip/hip_bf16.h>

// CausalSelfAttention on gfx950: bf16 MFMA pipeline, flash v3.
// x(4,2048,1024)f32, Wqkv(1024,3072)f32, Wproj(1024,1024)f32
// out = [ y (8192*1024) | k (4,16,2048,64) | v (4,16,2048,64) ] fp32
//
// R4: qkv GEMM = faithful m201 8-phase port. BM=BN=256, BK=64, 8 waves
// (2Mx4N, per-wave 128x64 = 64 MFMA/K-tile), LDS 128KB dbuf, 16-MFMA phases,
// half-tile staging 2 gld_lds/phase, vmcnt(4) only at ph4/ph8 (never drains
// mid-loop), lgkmcnt(0) after each barrier. Zero-conflict chunk-XOR layout
// (verified R1/R3). proj (R1 core) / flash (R3 dbuf) / prep unchanged.

typedef __bf16 bf16;
typedef __attribute__((ext_vector_type(8))) __bf16 bf16x8;
typedef __attribute__((ext_vector_type(4))) __bf16 bf16x4;
typedef __attribute__((ext_vector_type(4))) float f32x4;

#define AS_G __attribute__((address_space(1)))
#define AS_L __attribute__((address_space(3)))

// q pre-scale: 1/sqrt(64) * log2(e)  (softmax done in base-2)
#define QSCALE 0.1803368801111204f

__device__ __forceinline__ void gld_lds16(const bf16* g, bf16* l) {
  __builtin_amdgcn_global_load_lds((const AS_G void*)g, (AS_L void*)l, 16, 0, 0);
}

#define BAR() __builtin_amdgcn_s_barrier()
#define LGKM0() asm volatile("s_waitcnt lgkmcnt(0)" ::: "memory")
#define VMC(n) asm volatile("s_waitcnt vmcnt(" #n ")" ::: "memory")

// ---------- fused prep: cast x (f32->bf16) + transpose both weights ----------
__global__ __launch_bounds__(256) void k_prep(const float* __restrict__ x, bf16* __restrict__ xb,
                                              const float* __restrict__ Wqkv, bf16* __restrict__ wqkvT,
                                              const float* __restrict__ Wproj, bf16* __restrict__ wprojT) {
  __shared__ float tile[32][33];
  const int bid = blockIdx.x, tid = threadIdx.x;
  if (bid < 4096) {  // cast: 8 elems/thread
    int i = (bid * 256 + tid) * 8;
    float4 a = *(const float4*)(x + i);
    float4 b = *(const float4*)(x + i + 4);
    bf16x8 o;
    o[0] = (bf16)a.x; o[1] = (bf16)a.y; o[2] = (bf16)a.z; o[3] = (bf16)a.w;
    o[4] = (bf16)b.x; o[5] = (bf16)b.y; o[6] = (bf16)b.z; o[7] = (bf16)b.w;
    *(bf16x8*)(xb + i) = o;
    return;
  }
  // transpose W [K=1024][N] f32 -> Wt [N][K] bf16, 32x32 tiles
  const float* in; bf16* out; int N, t;
  if (bid < 7168) { t = bid - 4096; N = 3072; in = Wqkv; out = wqkvT; }
  else            { t = bid - 7168; N = 1024; in = Wproj; out = wprojT; }
  const int nbx = N >> 5;
  const int bx = (t % nbx) * 32, by = (t / nbx) * 32;
  const int tx = tid & 31, ty = tid >> 5;  // (32,8)
#pragma unroll
  for (int i = 0; i < 4; ++i)
    tile[ty + i * 8][tx] = in[(size_t)(by + ty + i * 8) * N + bx + tx];
  __syncthreads();
#pragma unroll
  for (int i = 0; i < 4; ++i)
    out[(size_t)(bx + ty + i * 8) * 1024 + by + tx] = (bf16)tile[tx][ty + i * 8];
}

// ============ qkv core: 256x256 BK=64 8-phase (m201-faithful) ============
// 512 thr = 8 waves (2M x 4N), per-wave 128x64 (8x4 frags), 64 MFMA/K-tile.
// LDS: A 2slots x 16384 elems (64KB), B same (64KB). K=1024 -> 16 tiles,
// 8 iterations x (even tile -> slot0, odd tile -> slot1).
// Layout: row r (64 elems), chunk slot p holds global chunk p ^ (r&7)
// (verified zero-conflict). Staging: thread u -> row u>>3 of seg, slot u&7,
// pre-swizzled global source chunk (u&7)^((u>>3)&7); dest linear = base+u*16B.
//
// Phase schedule per iter (e=2t slot0, o=2t+1 slot1, e'=2t+2, o'=2t+3):
//  ph1: rd aL(e),b01(e)   | stage B(o)s01  | MFMA mh0xnh0
//  ph2: rd aH(e)          | stage B(o)s23  | MFMA mh1xnh0
//  ph3: rd b23(e)         | stage A(e')s01 | MFMA mh1xnh1
//  ph4:                   | stage A(e')s23 | MFMA mh0xnh1 | vmcnt(4)
//  ph5: rd aL(o),b01(o)   | stage B(e')s01 | MFMA mh0xnh0
//  ph6: rd aH(o)          | stage B(e')s23 | MFMA mh1xnh0
//  ph7: rd b23(o)         | stage A(o')s01 | MFMA mh1xnh1
//  ph8:                   | stage A(o')s23 | MFMA mh0xnh1 | vmcnt(4)
// Each phase: [reads; stages; BAR; LGKM0; setprio1; 16 MFMA; setprio0;
// (vmcnt); BAR]. Write-after-read safety: a region staged in phase p was
// last read in phase <= p-1, whose reads are lgkm-drained before that
// phase's trailing barrier, which the stager passed. Read-after-write:
// vmcnt(4)+BAR leaves only the 4 newest loads in flight; everything a
// subsequent phase reads is older -> complete. Last iter: vmcnt(0).
__device__ __forceinline__ void gemm_core_8ph(const bf16* __restrict__ A,
                                              const bf16* __restrict__ Bt,
                                              int m0, int n0,
                                              bf16* As, bf16* Bs,
                                              f32x4 acc[8][4]) {
  const int tid = threadIdx.x;
  const int w = tid >> 6, lane = tid & 63, lo = lane & 15, hi = lane >> 4;
  const int wm = w >> 2, wn = w & 3;
  const int row64 = tid >> 3;
  const int g = (tid & 7) ^ (row64 & 7);
  const bf16* ga = A + (size_t)(m0 + row64) * 1024 + g * 8;
  const bf16* gb = Bt + (size_t)(n0 + row64) * 1024 + g * 8;
  bf16* Ad = As + tid * 8;
  bf16* Bd = Bs + tid * 8;
  const int aoff = (wm * 128 + lo) * 64;
  const int boff = (wn * 64 + lo) * 64;
  const int sw0 = (hi ^ (lo & 7)) * 8;
  const int sw1 = ((4 + hi) ^ (lo & 7)) * 8;

#define SGA(kt, s, slot) gld_lds16(ga + (size_t)(s) * 65536 + (size_t)(kt) * 64, Ad + (slot) * 16384 + (s) * 4096)
#define SGB(kt, s, slot) gld_lds16(gb + (size_t)(s) * 65536 + (size_t)(kt) * 64, Bd + (slot) * 16384 + (s) * 4096)
#define RDA(dst, slot, mi, ks) dst = *(const bf16x8*)(As + (slot) * 16384 + aoff + (mi) * 1024 + ((ks) ? sw1 : sw0))
#define RDB(dst, slot, ni, ks) dst = *(const bf16x8*)(Bs + (slot) * 16384 + boff + (ni) * 1024 + ((ks) ? sw1 : sw0))
#define MM16(mb, nb, AF, BF)                                                            \
  _Pragma("unroll") for (int ks = 0; ks < 2; ++ks)                                      \
  _Pragma("unroll") for (int mi = 0; mi < 4; ++mi)                                      \
  _Pragma("unroll") for (int ni = 0; ni < 2; ++ni)                                      \
    acc[(mb) + mi][(nb) + ni] = __builtin_amdgcn_mfma_f32_16x16x32_bf16(                \
        AF[mi][ks], BF[ni][ks], acc[(mb) + mi][(nb) + ni], 0, 0, 0);

  // prologue: A(0), B(0) -> slot0; A(1) -> slot1. vmcnt(4) leaves A(1) in flight.
  SGA(0, 0, 0); SGA(0, 1, 0); SGA(0, 2, 0); SGA(0, 3, 0);
  SGB(0, 0, 0); SGB(0, 1, 0); SGB(0, 2, 0); SGB(0, 3, 0);
  SGA(1, 0, 1); SGA(1, 1, 1); SGA(1, 2, 1); SGA(1, 3, 1);
  VMC(4); BAR();

  bf16x8 aL[4][2], aH[4][2], bb[2][2];
#pragma unroll 1
  for (int it = 0; it < 8; ++it) {
    const int o1 = 2 * it + 1, e2 = 2 * it + 2, o2 = 2 * it + 3;
    const bool st = (it < 7);
    // ---- ph1
#pragma unroll
    for (int mi = 0; mi < 4; ++mi) { RDA(aL[mi][0], 0, mi, 0); RDA(aL[mi][1], 0, mi, 1); }
#pragma unroll
    for (int ni = 0; ni < 2; ++ni) { RDB(bb[ni][0], 0, ni, 0); RDB(bb[ni][1], 0, ni, 1); }
    SGB(o1, 0, 1); SGB(o1, 1, 1);
    BAR(); LGKM0();
    __builtin_amdgcn_s_setprio(1); MM16(0, 0, aL, bb); __builtin_amdgcn_s_setprio(0);
    BAR();
    // ---- ph2
#pragma unroll
    for (int mi = 0; mi < 4; ++mi) { RDA(aH[mi][0], 0, 4 + mi, 0); RDA(aH[mi][1], 0, 4 + mi, 1); }
    SGB(o1, 2, 1); SGB(o1, 3, 1);
    BAR(); LGKM0();
    __builtin_amdgcn_s_setprio(1); MM16(4, 0, aH, bb); __builtin_amdgcn_s_setprio(0);
    BAR();
    // ---- ph3
#pragma unroll
    for (int ni = 0; ni < 2; ++ni) { RDB(bb[ni][0], 0, 2 + ni, 0); RDB(bb[ni][1], 0, 2 + ni, 1); }
    if (st) { SGA(e2, 0, 0); SGA(e2, 1, 0); }
    BAR(); LGKM0();
    __builtin_amdgcn_s_setprio(1); MM16(4, 2, aH, bb); __builtin_amdgcn_s_setprio(0);
    BAR();
    // ---- ph4
    if (st) { SGA(e2, 2, 0); SGA(e2, 3, 0); }
    BAR(); LGKM0();
    __builtin_amdgcn_s_setprio(1); MM16(0, 2, aL, bb); __builtin_amdgcn_s_setprio(0);
    if (st) { VMC(4); } else { VMC(0); }
    BAR();
    // ---- ph5
#pragma unroll
    for (int mi = 0; mi < 4; ++mi) { RDA(aL[mi][0], 1, mi, 0); RDA(aL[mi][1], 1, mi, 1); }
#pragma unroll
    for (int ni = 0; ni < 2; ++ni) { RDB(bb[ni][0], 1, ni, 0); RDB(bb[ni][1], 1, ni, 1); }
    if (st) { SGB(e2, 0, 0); SGB(e2, 1, 0); }
    BAR(); LGKM0();
    __builtin_amdgcn_s_setprio(1); MM16(0, 0, aL, bb); __builtin_amdgcn_s_setprio(0);
    BAR();
    // ---- ph6
#pragma unroll
    for (int mi = 0; mi < 4; ++mi) { RDA(aH[mi][0], 1, 4 + mi, 0); RDA(aH[mi][1], 1, 4 + mi, 1); }
    if (st) { SGB(e2, 2, 0); SGB(e2, 3, 0); }
    BAR(); LGKM0();
    __builtin_amdgcn_s_setprio(1); MM16(4, 0, aH, bb); __builtin_amdgcn_s_setprio(0);
    BAR();
    // ---- ph7
#pragma unroll
    for (int ni = 0; ni < 2; ++ni) { RDB(bb[ni][0], 1, 2 + ni, 0); RDB(bb[ni][1], 1, 2 + ni, 1); }
    if (st) { SGA(o2, 0, 1); SGA(o2, 1, 1); }
    BAR(); LGKM0();
    __builtin_amdgcn_s_setprio(1); MM16(4, 2, aH, bb); __builtin_amdgcn_s_setprio(0);
    BAR();
    // ---- ph8
    if (st) { SGA(o2, 2, 1); SGA(o2, 3, 1); }
    BAR(); LGKM0();
    __builtin_amdgcn_s_setprio(1); MM16(0, 2, aL, bb); __builtin_amdgcn_s_setprio(0);
    if (st) { VMC(4); } else { VMC(0); }
    BAR();
  }
#undef SGA
#undef SGB
#undef RDA
#undef RDB
#undef MM16
}

// -------- GEMM1: qkv = x @ Wqkv; epilogue scatters q/k bf16, k/v fp32, V^T bf16 --------
__global__ __launch_bounds__(512, 2) void k_gemm_qkv(const bf16* __restrict__ x,
                                                     const bf16* __restrict__ WqkvT,
                                                     bf16* __restrict__ qb, bf16* __restrict__ kb,
                                                     bf16* __restrict__ vtb,
                                                     float* __restrict__ outk, float* __restrict__ outv) {
  __shared__ bf16 As[32768], Bs[32768];  // 128 KB
  // bijective XCD swizzle (384 % 8 == 0): 48 contiguous tiles per XCD
  int id = blockIdx.x;
  int swz = (id & 7) * 48 + (id >> 3);
  int by = swz / 12, bx = swz - by * 12;
  int m0 = by * 256, n0 = bx * 256;
  f32x4 acc[8][4] = {};
  gemm_core_8ph(x, WqkvT, m0, n0, As, Bs, acc);
  const int tid = threadIdx.x;
  const int w = tid >> 6, lane = tid & 63, lo = lane & 15, hi = lane >> 4;
  const int wm = w >> 2, wn = w & 3;
#pragma unroll
  for (int mi = 0; mi < 8; ++mi) {
    int growbase = m0 + wm * 128 + mi * 16 + hi * 4;  // b*2048 + t0, 4 consecutive t
    int bb = growbase >> 11, t0 = growbase & 2047;
#pragma unroll
    for (int ni = 0; ni < 4; ++ni) {
      int gcol = n0 + wn * 64 + ni * 16 + lo;          // 0..3071
      int part = gcol >> 10;                           // 0=q 1=k 2=v (uniform per block)
      int cc = gcol & 1023, h = cc >> 6, d = cc & 63;
      size_t idx0 = ((size_t)(bb * 16 + h) * 2048 + t0) * 64 + d;
      if (part == 0) {
#pragma unroll
        for (int r = 0; r < 4; ++r) qb[idx0 + (size_t)r * 64] = (bf16)(acc[mi][ni][r] * QSCALE);
      } else if (part == 1) {
#pragma unroll
        for (int r = 0; r < 4; ++r) {
          float val = acc[mi][ni][r];
          kb[idx0 + (size_t)r * 64] = (bf16)val;
          outk[idx0 + (size_t)r * 64] = val;
        }
      } else {
        bf16x4 pk;
#pragma unroll
        for (int r = 0; r < 4; ++r) {
          float val = acc[mi][ni][r];
          outv[idx0 + (size_t)r * 64] = val;
          pk[r] = (bf16)val;
        }
        *(bf16x4*)(vtb + ((size_t)(bb * 16 + h) * 64 + d) * 2048 + t0) = pk;
      }
    }
  }
}

// ---------------- proj core: R1-proven 256x128 4-phase (unchanged) ----------------
__device__ __forceinline__ void gemm_main_256x128(const bf16* __restrict__ A,
                                                  const bf16* __restrict__ Bt,
                                                  int m0, int n0,
                                                  bf16* As, bf16* Bs,
                                                  f32x4 acc[4][4]) {
  const int tid = threadIdx.x;
  const int w = tid >> 6, lane = tid & 63, lo = lane & 15, hi = lane >> 4;
  const int wm = w >> 1, wn = w & 1;
  const int urow = tid >> 3;
  const int gsw = (tid & 7) ^ (urow & 7);
  const bf16* ga = A + (size_t)(m0 + urow) * 1024 + gsw * 8;
  const bf16* gb = Bt + (size_t)(n0 + urow) * 1024 + gsw * 8;
  const int p0 = hi ^ (lo & 7);
  const int aRow = wm * 64 + lo;
  const int bRow = wn * 64 + lo;

#define STAGE_A2(t, bufi, s0) do {                                                              \
    gld_lds16(ga + (size_t)(s0) * 65536 + (t) * 64,                                             \
              As + (bufi) * 16384 + (s0) * 4096 + w * 512);                                     \
    gld_lds16(ga + (size_t)((s0) + 1) * 65536 + (t) * 64,                                       \
              As + (bufi) * 16384 + ((s0) + 1) * 4096 + w * 512);                               \
  } while (0)
#define STAGE_B2(t, bufi) do {                                                                  \
    gld_lds16(gb + (t) * 64, Bs + (bufi) * 8192 + w * 512);                                     \
    gld_lds16(gb + 65536 + (t) * 64, Bs + (bufi) * 8192 + 4096 + w * 512);                      \
  } while (0)

  STAGE_A2(0, 0, 0); STAGE_A2(0, 0, 2); STAGE_B2(0, 0);
  STAGE_A2(1, 1, 0); STAGE_A2(1, 1, 2); STAGE_B2(1, 1);

  bf16x8 a[2][2], b[4][2];
  int buf = 0, sbuf = 2;
#pragma unroll 1
  for (int t = 0; t < 16; ++t) {
    if (t < 15) { VMC(6); } else { VMC(0); }
    BAR();
    const bf16* Ab = As + buf * 16384;
    const bf16* Bb = Bs + buf * 8192;

#pragma unroll
    for (int mi = 0; mi < 2; ++mi) {
      const bf16* r = Ab + (aRow + mi * 16) * 64;
      a[mi][0] = *(const bf16x8*)(r + p0 * 8);
      a[mi][1] = *(const bf16x8*)(r + (p0 ^ 4) * 8);
    }
#pragma unroll
    for (int ni = 0; ni < 2; ++ni) {
      const bf16* r = Bb + (bRow + ni * 16) * 64;
      b[ni][0] = *(const bf16x8*)(r + p0 * 8);
      b[ni][1] = *(const bf16x8*)(r + (p0 ^ 4) * 8);
    }
    if (t < 14) STAGE_A2(t + 2, sbuf, 0);
    BAR();
    __builtin_amdgcn_s_setprio(1);
#pragma unroll
    for (int ks = 0; ks < 2; ++ks)
#pragma unroll
      for (int mi = 0; mi < 2; ++mi)
#pragma unroll
        for (int ni = 0; ni < 2; ++ni)
          acc[mi][ni] = __builtin_amdgcn_mfma_f32_16x16x32_bf16(a[mi][ks], b[ni][ks], acc[mi][ni], 0, 0, 0);
    __builtin_amdgcn_s_setprio(0);
    BAR();

#pragma unroll
    for (int ni = 0; ni < 2; ++ni) {
      const bf16* r = Bb + (bRow + (ni + 2) * 16) * 64;
      b[ni + 2][0] = *(const bf16x8*)(r + p0 * 8);
      b[ni + 2][1] = *(const bf16x8*)(r + (p0 ^ 4) * 8);
    }
    if (t < 14) STAGE_A2(t + 2, sbuf, 2);
    BAR();
    __builtin_amdgcn_s_setprio(1);
#pragma unroll
    for (int ks = 0; ks < 2; ++ks)
#pragma unroll
      for (int mi = 0; mi < 2; ++mi)
#pragma unroll
        for (int ni = 0; ni < 2; ++ni)
          acc[mi][ni + 2] = __builtin_amdgcn_mfma_f32_16x16x32_bf16(a[mi][ks], b[ni + 2][ks], acc[mi][ni + 2], 0, 0, 0);
    __builtin_amdgcn_s_setprio(0);
    BAR();

#pragma unroll
    for (int mi = 0; mi < 2; ++mi) {
      const bf16* r = Ab + (aRow + (mi + 2) * 16) * 64;
      a[mi][0] = *(const bf16x8*)(r + p0 * 8);
      a[mi][1] = *(const bf16x8*)(r + (p0 ^ 4) * 8);
    }
    if (t < 14) STAGE_B2(t + 2, sbuf);
    BAR();
    __builtin_amdgcn_s_setprio(1);
#pragma unroll
    for (int ks = 0; ks < 2; ++ks)
#pragma unroll
      for (int mi = 0; mi < 2; ++mi)
#pragma unroll
        for (int ni = 0; ni < 2; ++ni)
          acc[mi + 2][ni + 2] = __builtin_amdgcn_mfma_f32_16x16x32_bf16(a[mi][ks], b[ni + 2][ks], acc[mi + 2][ni + 2], 0, 0, 0);
    __builtin_amdgcn_s_setprio(0);
    BAR();

    __builtin_amdgcn_s_setprio(1);
#pragma unroll
    for (int ks = 0; ks < 2; ++ks)
#pragma unroll
      for (int mi = 0; mi < 2; ++mi)
#pragma unroll
        for (int ni = 0; ni < 2; ++ni)
          acc[mi + 2][ni] = __builtin_amdgcn_mfma_f32_16x16x32_bf16(a[mi][ks], b[ni][ks], acc[mi + 2][ni], 0, 0, 0);
    __builtin_amdgcn_s_setprio(0);

    buf = (buf == 2) ? 0 : buf + 1;
    sbuf = (sbuf == 2) ? 0 : sbuf + 1;
  }
#undef STAGE_A2
#undef STAGE_B2
}

// ---------------- GEMM2: out_y = y_att @ Wproj ----------------
__global__ __launch_bounds__(512, 2) void k_gemm_proj(const bf16* __restrict__ yb,
                                                      const bf16* __restrict__ WprojT,
                                                      float* __restrict__ out) {
  __shared__ bf16 As[49152], Bs[24576];  // 144 KB
  int id = blockIdx.x;
  int swz = (id & 7) * 32 + (id >> 3);   // 256 % 8 == 0
  int by = swz >> 3, bx = swz & 7;
  int m0 = by * 256, n0 = bx * 128;
  f32x4 acc[4][4] = {};
  gemm_main_256x128(yb, WprojT, m0, n0, As, Bs, acc);
  const int tid = threadIdx.x;
  const int w = tid >> 6, lane = tid & 63, lo = lane & 15, hi = lane >> 4;
  const int wm = w >> 1, wn = w & 1;
#pragma unroll
  for (int mi = 0; mi < 4; ++mi)
#pragma unroll
    for (int ni = 0; ni < 4; ++ni)
#pragma unroll
      for (int r = 0; r < 4; ++r) {
        int grow = m0 + wm * 64 + mi * 16 + hi * 4 + r;
        int gcol = n0 + wn * 64 + ni * 16 + lo;
        out[(size_t)grow * 1024 + gcol] = acc[mi][ni][r];
      }
}

// ---------------- flash v3, K/V double-buffered (unchanged) ----------------
#define PSTR 76

__device__ __forceinline__ void p_store(f32x4 sacc[4], bool mask,
                                        int w, int lo, int hi, bf16* psrow) {
  if (mask) {
#pragma unroll
    for (int nt = 0; nt < 4; ++nt)
#pragma unroll
      for (int r = 0; r < 4; ++r)
        if (nt * 16 + hi * 4 + r > w * 16 + lo) sacc[nt][r] = -1e30f;
  }
#pragma unroll
  for (int nt = 0; nt < 4; ++nt) {
    bf16x4 pk;
#pragma unroll
    for (int r = 0; r < 4; ++r) pk[r] = (bf16)__builtin_amdgcn_exp2f(sacc[nt][r]);
    *(bf16x4*)(psrow + (w * 16 + lo) * PSTR + nt * 16 + hi * 4) = pk;
  }
}

__device__ __forceinline__ void write_y(bf16* __restrict__ y, int b, int h, int qrow,
                                        int hi, const f32x4 o[4], float inv) {
  size_t base = ((size_t)b * 2048 + qrow) * 1024 + h * 64;
#pragma unroll
  for (int mt = 0; mt < 4; ++mt) {
    bf16x4 yk;
#pragma unroll
    for (int r = 0; r < 4; ++r) yk[r] = (bf16)(o[mt][r] * inv);
    *(bf16x4*)(y + base + mt * 16 + hi * 4) = yk;
  }
}

__global__ __launch_bounds__(256, 4) void k_flash(const bf16* __restrict__ q,
                                                  const bf16* __restrict__ k,
                                                  const bf16* __restrict__ vt,
                                                  bf16* __restrict__ y) {
  __shared__ bf16 Ks[2 * 4096];      // [buf][s][d], chunk-swizzled by s&7
  __shared__ bf16 Vs[2 * 4096];      // [buf][d][s] (V^T), chunk-swizzled by d&7
  __shared__ bf16 Ones[16 * 64];     // row 0 = 1.0, rows 1..15 = 0 (l-row operand)
  __shared__ bf16 Ps[128 * PSTR];    // [q_local][s]: rows 0..63 tile A, 64..127 tile B
  const int bi = blockIdx.x;
  const int slot = bi >> 3;
  const int bh = (bi & 7) + 8 * (slot >> 4);
  const int j = slot & 15;
  const int jA = j, jB = 31 - j;
  const int tid = threadIdx.x, w = tid >> 6, lane = tid & 63, lo = lane & 15, hi = lane >> 4;
  const bf16* qp = q + (size_t)bh * 2048 * 64;
  const bf16* kp = k + (size_t)bh * 2048 * 64;
  const bf16* vtp = vt + (size_t)bh * 64 * 2048;

  {
    int rr = tid >> 4, c = (tid & 15) * 4;
    bf16x4 z;
    bf16 v1 = (rr == 0) ? (bf16)1.0f : (bf16)0.0f;
    z[0] = v1; z[1] = v1; z[2] = v1; z[3] = v1;
    *(bf16x4*)(Ones + rr * 64 + c) = z;
  }

#pragma unroll
  for (int p = 0; p < 2; ++p) {
    int u = tid + 256 * p;
    int row = u >> 3, g = (u & 7) ^ (row & 7);
    gld_lds16(kp + (size_t)row * 64 + g * 8, Ks + p * 2048 + w * 512);
    gld_lds16(vtp + (size_t)row * 2048 + g * 8, Vs + p * 2048 + w * 512);
  }

  bf16x8 qfA[2], qfB[2];
  {
    int qA = jA * 64 + w * 16 + lo;
    int qB = jB * 64 + w * 16 + lo;
    qfA[0] = *(const bf16x8*)(qp + (size_t)qA * 64 + hi * 8);
    qfA[1] = *(const bf16x8*)(qp + (size_t)qA * 64 + 32 + hi * 8);
    qfB[0] = *(const bf16x8*)(qp + (size_t)qB * 64 + hi * 8);
    qfB[1] = *(const bf16x8*)(qp + (size_t)qB * 64 + 32 + hi * 8);
  }
  f32x4 oA[4] = {}, oB[4] = {};
  f32x4 oLA = {}, oLB = {};

  VMC(0);
  BAR();

  for (int st = 0; st <= jB; ++st) {
    const int cb = (st & 1) * 4096;
    const int nb = cb ^ 4096;

    bf16x8 kf[4][2];
#pragma unroll
    for (int nt = 0; nt < 4; ++nt)
#pragma unroll
      for (int ks = 0; ks < 2; ++ks)
        kf[nt][ks] = *(const bf16x8*)(Ks + cb + (nt * 16 + lo) * 64 + ((ks * 4 + hi) ^ (lo & 7)) * 8);

    if (st < jB) {
      const int s1 = (st + 1) * 64;
#pragma unroll
      for (int p = 0; p < 2; ++p) {
        int u = tid + 256 * p;
        int row = u >> 3, g = (u & 7) ^ (row & 7);
        gld_lds16(kp + (size_t)(s1 + row) * 64 + g * 8, Ks + nb + p * 2048 + w * 512);
        gld_lds16(vtp + (size_t)row * 2048 + s1 + g * 8, Vs + nb + p * 2048 + w * 512);
      }
    }

    const bool actA = (st <= jA);
    f32x4 saccA[4] = {}, saccB[4] = {};
    __builtin_amdgcn_s_setprio(1);
    if (actA) {
#pragma unroll
      for (int nt = 0; nt < 4; ++nt)
#pragma unroll
        for (int ks = 0; ks < 2; ++ks)
          saccA[nt] = __builtin_amdgcn_mfma_f32_16x16x32_bf16(kf[nt][ks], qfA[ks], saccA[nt], 0, 0, 0);
    }
#pragma unroll
    for (int nt = 0; nt < 4; ++nt)
#pragma unroll
      for (int ks = 0; ks < 2; ++ks)
        saccB[nt] = __builtin_amdgcn_mfma_f32_16x16x32_bf16(kf[nt][ks], qfB[ks], saccB[nt], 0, 0, 0);
    __builtin_amdgcn_s_setprio(0);
    if (actA) p_store(saccA, st == jA, w, lo, hi, Ps);
    p_store(saccB, st == jB, w, lo, hi, Ps + 64 * PSTR);
    LGKM0();

    bf16x8 pfA[2], pfB[2];
#pragma unroll
    for (int ks = 0; ks < 2; ++ks) {
      pfB[ks] = *(const bf16x8*)(Ps + (64 + w * 16 + lo) * PSTR + ks * 32 + hi * 8);
      if (actA) pfA[ks] = *(const bf16x8*)(Ps + (w * 16 + lo) * PSTR + ks * 32 + hi * 8);
    }
    __builtin_amdgcn_s_setprio(1);
#pragma unroll
    for (int mt = 0; mt < 5; ++mt) {
#pragma unroll
      for (int ks = 0; ks < 2; ++ks) {
        int row = mt * 16 + lo;
        bf16x8 vf = (mt < 4)
            ? *(const bf16x8*)(Vs + cb + row * 64 + ((ks * 4 + hi) ^ (row & 7)) * 8)
            : *(const bf16x8*)(Ones + lo * 64 + ((ks * 4 + hi) ^ (lo & 7)) * 8);
        if (mt < 4) {
          oB[mt] = __builtin_amdgcn_mfma_f32_16x16x32_bf16(vf, pfB[ks], oB[mt], 0, 0, 0);
          if (actA) oA[mt] = __builtin_amdgcn_mfma_f32_16x16x32_bf16(vf, pfA[ks], oA[mt], 0, 0, 0);
        } else {
          oLB = __builtin_amdgcn_mfma_f32_16x16x32_bf16(vf, pfB[ks], oLB, 0, 0, 0);
          if (actA) oLA = __builtin_amdgcn_mfma_f32_16x16x32_bf16(vf, pfA[ks], oLA, 0, 0, 0);
        }
      }
    }
    __builtin_amdgcn_s_setprio(0);

    VMC(0);
    BAR();
  }

  const int b = bh >> 4, h = bh & 15;
  float lA = __shfl(oLA[0], lo, 64);
  float lB = __shfl(oLB[0], lo, 64);
  write_y(y, b, h, jA * 64 + w * 16 + lo, hi, oA, 1.0f / lA);
  write_y(y, b, h, jB * 64 + w * 16 + lo, hi, oB, 1.0f / lB);
}

// ---------------------------------------------------------------------------
extern "C" void kernel_launch(void* const* d_in, const int* in_sizes, int n_in,
                              void* d_out, int out_size, void* d_ws, size_t ws_size,
                              hipStream_t stream) {
  const float* x = (const float*)d_in[0];
  const float* Wqkv = (const float*)d_in[1];
  const float* Wproj = (const float*)d_in[2];
  float* out = (float*)d_out;

  const size_t YSZ = (size_t)8192 * 1024;
  char* ws = (char*)d_ws;
  bf16* xb = (bf16*)ws;      ws += (size_t)8192 * 1024 * 2;
  bf16* wqkvT = (bf16*)ws;   ws += (size_t)3072 * 1024 * 2;
  bf16* wprojT = (bf16*)ws;  ws += (size_t)1024 * 1024 * 2;
  bf16* qb = (bf16*)ws;      ws += (size_t)64 * 2048 * 64 * 2;
  bf16* kb = (bf16*)ws;      ws += (size_t)64 * 2048 * 64 * 2;
  bf16* vtb = (bf16*)ws;     ws += (size_t)64 * 2048 * 64 * 2;
  bf16* yb = (bf16*)ws;      // 88 MB total

  float* outy = out;
  float* outk = out + YSZ;
  float* outv = out + 2 * YSZ;

  k_prep<<<8192, 256, 0, stream>>>(x, xb, Wqkv, wqkvT, Wproj, wprojT);
  k_gemm_qkv<<<384, 512, 0, stream>>>(xb, wqkvT, qb, kb, vtb, outk, outv);
  k_flash<<<1024, 256, 0, stream>>>(qb, kb, vtb, yb);
  k_gemm_proj<<<256, 512, 0, stream>>>(yb, wprojT, outy);
}

// Round 5
// 302.344 us; speedup vs baseline: 1.0058x; 1.0058x over previous
//
#include <hip/hip_runtime.h>
#include <hip/hip_bf16.h>

// CausalSelfAttention on gfx950: bf16 MFMA pipeline, flash v3.
// x(4,2048,1024)f32, Wqkv(1024,3072)f32, Wproj(1024,1024)f32
// out = [ y (8192*1024) | k (4,16,2048,64) | v (4,16,2048,64) ] fp32
//
// R5: qkv reverted to the proven R3 core (256x128, BK=64, 4-phase counted
// vmcnt(6), grid 768 = 3 exact CU-rounds, 83us / 0 conflicts). Flash gets
// the j-balance remap: co-resident blocks previously all shared the same j
// (tile count 32-j) -> per-CU load imbalance 1.31x. New map flips j -> 15-v
// on bit8 of blockIdx so each CU hosts two (32-v)-step and two (17+v)-step
// blocks = constant 98 steps/CU. bh / XCD locality unchanged.

typedef __bf16 bf16;
typedef __attribute__((ext_vector_type(8))) __bf16 bf16x8;
typedef __attribute__((ext_vector_type(4))) __bf16 bf16x4;
typedef __attribute__((ext_vector_type(4))) float f32x4;

#define AS_G __attribute__((address_space(1)))
#define AS_L __attribute__((address_space(3)))

// q pre-scale: 1/sqrt(64) * log2(e)  (softmax done in base-2)
#define QSCALE 0.1803368801111204f

__device__ __forceinline__ void gld_lds16(const bf16* g, bf16* l) {
  __builtin_amdgcn_global_load_lds((const AS_G void*)g, (AS_L void*)l, 16, 0, 0);
}

#define BAR() __builtin_amdgcn_s_barrier()
#define LGKM0() asm volatile("s_waitcnt lgkmcnt(0)" ::: "memory")
#define VMC(n) asm volatile("s_waitcnt vmcnt(" #n ")" ::: "memory")

// ---------- fused prep: cast x (f32->bf16) + transpose both weights ----------
__global__ __launch_bounds__(256) void k_prep(const float* __restrict__ x, bf16* __restrict__ xb,
                                              const float* __restrict__ Wqkv, bf16* __restrict__ wqkvT,
                                              const float* __restrict__ Wproj, bf16* __restrict__ wprojT) {
  __shared__ float tile[32][33];
  const int bid = blockIdx.x, tid = threadIdx.x;
  if (bid < 4096) {  // cast: 8 elems/thread
    int i = (bid * 256 + tid) * 8;
    float4 a = *(const float4*)(x + i);
    float4 b = *(const float4*)(x + i + 4);
    bf16x8 o;
    o[0] = (bf16)a.x; o[1] = (bf16)a.y; o[2] = (bf16)a.z; o[3] = (bf16)a.w;
    o[4] = (bf16)b.x; o[5] = (bf16)b.y; o[6] = (bf16)b.z; o[7] = (bf16)b.w;
    *(bf16x8*)(xb + i) = o;
    return;
  }
  // transpose W [K=1024][N] f32 -> Wt [N][K] bf16, 32x32 tiles
  const float* in; bf16* out; int N, t;
  if (bid < 7168) { t = bid - 4096; N = 3072; in = Wqkv; out = wqkvT; }
  else            { t = bid - 7168; N = 1024; in = Wproj; out = wprojT; }
  const int nbx = N >> 5;
  const int bx = (t % nbx) * 32, by = (t / nbx) * 32;
  const int tx = tid & 31, ty = tid >> 5;  // (32,8)
#pragma unroll
  for (int i = 0; i < 4; ++i)
    tile[ty + i * 8][tx] = in[(size_t)(by + ty + i * 8) * N + bx + tx];
  __syncthreads();
#pragma unroll
  for (int i = 0; i < 4; ++i)
    out[(size_t)(bx + ty + i * 8) * 1024 + by + tx] = (bf16)tile[tx][ty + i * 8];
}

// ---------------- 256x128 4-phase counted-vmcnt GEMM mainloop ----------------
// (proven: 83us qkv, zero LDS bank conflicts)
// 512 threads = 8 waves (4M x 2N), per-wave output 64x64. BK=64.
// LDS: 3 buffers x (A 32KB + B 16KB) = 144KB. Stage t+2 spread over phases;
// boundary waits vmcnt(6) (tile t+1's 6 loads stay in flight).
__device__ __forceinline__ void gemm_main_256x128(const bf16* __restrict__ A,
                                                  const bf16* __restrict__ Bt,
                                                  int m0, int n0,
                                                  bf16* As, bf16* Bs,
                                                  f32x4 acc[4][4]) {
  const int tid = threadIdx.x;
  const int w = tid >> 6, lane = tid & 63, lo = lane & 15, hi = lane >> 4;
  const int wm = w >> 1, wn = w & 1;
  const int urow = tid >> 3;
  const int gsw = (tid & 7) ^ (urow & 7);
  const bf16* ga = A + (size_t)(m0 + urow) * 1024 + gsw * 8;
  const bf16* gb = Bt + (size_t)(n0 + urow) * 1024 + gsw * 8;
  const int p0 = hi ^ (lo & 7);
  const int aRow = wm * 64 + lo;
  const int bRow = wn * 64 + lo;

#define STAGE_A2(t, bufi, s0) do {                                                              \
    gld_lds16(ga + (size_t)(s0) * 65536 + (t) * 64,                                             \
              As + (bufi) * 16384 + (s0) * 4096 + w * 512);                                     \
    gld_lds16(ga + (size_t)((s0) + 1) * 65536 + (t) * 64,                                       \
              As + (bufi) * 16384 + ((s0) + 1) * 4096 + w * 512);                               \
  } while (0)
#define STAGE_B2(t, bufi) do {                                                                  \
    gld_lds16(gb + (t) * 64, Bs + (bufi) * 8192 + w * 512);                                     \
    gld_lds16(gb + 65536 + (t) * 64, Bs + (bufi) * 8192 + 4096 + w * 512);                      \
  } while (0)

  STAGE_A2(0, 0, 0); STAGE_A2(0, 0, 2); STAGE_B2(0, 0);
  STAGE_A2(1, 1, 0); STAGE_A2(1, 1, 2); STAGE_B2(1, 1);

  bf16x8 a[2][2], b[4][2];
  int buf = 0, sbuf = 2;
#pragma unroll 1
  for (int t = 0; t < 16; ++t) {
    if (t < 15) { VMC(6); } else { VMC(0); }
    BAR();
    const bf16* Ab = As + buf * 16384;
    const bf16* Bb = Bs + buf * 8192;

#pragma unroll
    for (int mi = 0; mi < 2; ++mi) {
      const bf16* r = Ab + (aRow + mi * 16) * 64;
      a[mi][0] = *(const bf16x8*)(r + p0 * 8);
      a[mi][1] = *(const bf16x8*)(r + (p0 ^ 4) * 8);
    }
#pragma unroll
    for (int ni = 0; ni < 2; ++ni) {
      const bf16* r = Bb + (bRow + ni * 16) * 64;
      b[ni][0] = *(const bf16x8*)(r + p0 * 8);
      b[ni][1] = *(const bf16x8*)(r + (p0 ^ 4) * 8);
    }
    if (t < 14) STAGE_A2(t + 2, sbuf, 0);
    BAR();
    __builtin_amdgcn_s_setprio(1);
#pragma unroll
    for (int ks = 0; ks < 2; ++ks)
#pragma unroll
      for (int mi = 0; mi < 2; ++mi)
#pragma unroll
        for (int ni = 0; ni < 2; ++ni)
          acc[mi][ni] = __builtin_amdgcn_mfma_f32_16x16x32_bf16(a[mi][ks], b[ni][ks], acc[mi][ni], 0, 0, 0);
    __builtin_amdgcn_s_setprio(0);
    BAR();

#pragma unroll
    for (int ni = 0; ni < 2; ++ni) {
      const bf16* r = Bb + (bRow + (ni + 2) * 16) * 64;
      b[ni + 2][0] = *(const bf16x8*)(r + p0 * 8);
      b[ni + 2][1] = *(const bf16x8*)(r + (p0 ^ 4) * 8);
    }
    if (t < 14) STAGE_A2(t + 2, sbuf, 2);
    BAR();
    __builtin_amdgcn_s_setprio(1);
#pragma unroll
    for (int ks = 0; ks < 2; ++ks)
#pragma unroll
      for (int mi = 0; mi < 2; ++mi)
#pragma unroll
        for (int ni = 0; ni < 2; ++ni)
          acc[mi][ni + 2] = __builtin_amdgcn_mfma_f32_16x16x32_bf16(a[mi][ks], b[ni + 2][ks], acc[mi][ni + 2], 0, 0, 0);
    __builtin_amdgcn_s_setprio(0);
    BAR();

#pragma unroll
    for (int mi = 0; mi < 2; ++mi) {
      const bf16* r = Ab + (aRow + (mi + 2) * 16) * 64;
      a[mi][0] = *(const bf16x8*)(r + p0 * 8);
      a[mi][1] = *(const bf16x8*)(r + (p0 ^ 4) * 8);
    }
    if (t < 14) STAGE_B2(t + 2, sbuf);
    BAR();
    __builtin_amdgcn_s_setprio(1);
#pragma unroll
    for (int ks = 0; ks < 2; ++ks)
#pragma unroll
      for (int mi = 0; mi < 2; ++mi)
#pragma unroll
        for (int ni = 0; ni < 2; ++ni)
          acc[mi + 2][ni + 2] = __builtin_amdgcn_mfma_f32_16x16x32_bf16(a[mi][ks], b[ni + 2][ks], acc[mi + 2][ni + 2], 0, 0, 0);
    __builtin_amdgcn_s_setprio(0);
    BAR();

    __builtin_amdgcn_s_setprio(1);
#pragma unroll
    for (int ks = 0; ks < 2; ++ks)
#pragma unroll
      for (int mi = 0; mi < 2; ++mi)
#pragma unroll
        for (int ni = 0; ni < 2; ++ni)
          acc[mi + 2][ni] = __builtin_amdgcn_mfma_f32_16x16x32_bf16(a[mi][ks], b[ni][ks], acc[mi + 2][ni], 0, 0, 0);
    __builtin_amdgcn_s_setprio(0);

    buf = (buf == 2) ? 0 : buf + 1;
    sbuf = (sbuf == 2) ? 0 : sbuf + 1;
  }
#undef STAGE_A2
#undef STAGE_B2
}

// -------- GEMM1: qkv = x @ Wqkv; epilogue scatters q/k bf16, k/v fp32, V^T bf16 --------
__global__ __launch_bounds__(512, 2) void k_gemm_qkv(const bf16* __restrict__ x,
                                                     const bf16* __restrict__ WqkvT,
                                                     bf16* __restrict__ qb, bf16* __restrict__ kb,
                                                     bf16* __restrict__ vtb,
                                                     float* __restrict__ outk, float* __restrict__ outv) {
  __shared__ bf16 As[49152], Bs[24576];  // 144 KB
  // bijective XCD swizzle (768 % 8 == 0)
  int id = blockIdx.x;
  int swz = (id & 7) * 96 + (id >> 3);
  int by = swz / 24, bx = swz - by * 24;
  int m0 = by * 256, n0 = bx * 128;
  f32x4 acc[4][4] = {};
  gemm_main_256x128(x, WqkvT, m0, n0, As, Bs, acc);
  const int tid = threadIdx.x;
  const int w = tid >> 6, lane = tid & 63, lo = lane & 15, hi = lane >> 4;
  const int wm = w >> 1, wn = w & 1;
#pragma unroll
  for (int mi = 0; mi < 4; ++mi) {
    int growbase = m0 + wm * 64 + mi * 16 + hi * 4;  // b*2048 + t0, 4 consecutive t
    int bb = growbase >> 11, t0 = growbase & 2047;
#pragma unroll
    for (int ni = 0; ni < 4; ++ni) {
      int gcol = n0 + wn * 64 + ni * 16 + lo;        // 0..3071
      int part = gcol >> 10;                         // 0=q 1=k 2=v (uniform per block)
      int cc = gcol & 1023, h = cc >> 6, d = cc & 63;
      size_t idx0 = ((size_t)(bb * 16 + h) * 2048 + t0) * 64 + d;
      if (part == 0) {
#pragma unroll
        for (int r = 0; r < 4; ++r) qb[idx0 + (size_t)r * 64] = (bf16)(acc[mi][ni][r] * QSCALE);
      } else if (part == 1) {
#pragma unroll
        for (int r = 0; r < 4; ++r) {
          float val = acc[mi][ni][r];
          kb[idx0 + (size_t)r * 64] = (bf16)val;
          outk[idx0 + (size_t)r * 64] = val;
        }
      } else {
        bf16x4 pk;
#pragma unroll
        for (int r = 0; r < 4; ++r) {
          float val = acc[mi][ni][r];
          outv[idx0 + (size_t)r * 64] = val;
          pk[r] = (bf16)val;
        }
        *(bf16x4*)(vtb + ((size_t)(bb * 16 + h) * 64 + d) * 2048 + t0) = pk;
      }
    }
  }
}

// ---------------- GEMM2: out_y = y_att @ Wproj ----------------
__global__ __launch_bounds__(512, 2) void k_gemm_proj(const bf16* __restrict__ yb,
                                                      const bf16* __restrict__ WprojT,
                                                      float* __restrict__ out) {
  __shared__ bf16 As[49152], Bs[24576];  // 144 KB
  int id = blockIdx.x;
  int swz = (id & 7) * 32 + (id >> 3);   // 256 % 8 == 0
  int by = swz >> 3, bx = swz & 7;
  int m0 = by * 256, n0 = bx * 128;
  f32x4 acc[4][4] = {};
  gemm_main_256x128(yb, WprojT, m0, n0, As, Bs, acc);
  const int tid = threadIdx.x;
  const int w = tid >> 6, lane = tid & 63, lo = lane & 15, hi = lane >> 4;
  const int wm = w >> 1, wn = w & 1;
#pragma unroll
  for (int mi = 0; mi < 4; ++mi)
#pragma unroll
    for (int ni = 0; ni < 4; ++ni)
#pragma unroll
      for (int r = 0; r < 4; ++r) {
        int grow = m0 + wm * 64 + mi * 16 + hi * 4 + r;
        int gcol = n0 + wn * 64 + ni * 16 + lo;
        out[(size_t)grow * 1024 + gcol] = acc[mi][ni][r];
      }
}

// ---------------- flash v3, K/V double-buffered + j-balanced ----------------
#define PSTR 76

__device__ __forceinline__ void p_store(f32x4 sacc[4], bool mask,
                                        int w, int lo, int hi, bf16* psrow) {
  if (mask) {
#pragma unroll
    for (int nt = 0; nt < 4; ++nt)
#pragma unroll
      for (int r = 0; r < 4; ++r)
        if (nt * 16 + hi * 4 + r > w * 16 + lo) sacc[nt][r] = -1e30f;
  }
#pragma unroll
  for (int nt = 0; nt < 4; ++nt) {
    bf16x4 pk;
#pragma unroll
    for (int r = 0; r < 4; ++r) pk[r] = (bf16)__builtin_amdgcn_exp2f(sacc[nt][r]);
    *(bf16x4*)(psrow + (w * 16 + lo) * PSTR + nt * 16 + hi * 4) = pk;
  }
}

__device__ __forceinline__ void write_y(bf16* __restrict__ y, int b, int h, int qrow,
                                        int hi, const f32x4 o[4], float inv) {
  size_t base = ((size_t)b * 2048 + qrow) * 1024 + h * 64;
#pragma unroll
  for (int mt = 0; mt < 4; ++mt) {
    bf16x4 yk;
#pragma unroll
    for (int r = 0; r < 4; ++r) yk[r] = (bf16)(o[mt][r] * inv);
    *(bf16x4*)(y + base + mt * 16 + hi * 4) = yk;
  }
}

__global__ __launch_bounds__(256, 4) void k_flash(const bf16* __restrict__ q,
                                                  const bf16* __restrict__ k,
                                                  const bf16* __restrict__ vt,
                                                  bf16* __restrict__ y) {
  __shared__ bf16 Ks[2 * 4096];      // [buf][s][d], chunk-swizzled by s&7
  __shared__ bf16 Vs[2 * 4096];      // [buf][d][s] (V^T), chunk-swizzled by d&7
  __shared__ bf16 Ones[16 * 64];     // row 0 = 1.0, rows 1..15 = 0 (l-row operand)
  __shared__ bf16 Ps[128 * PSTR];    // [q_local][s]: rows 0..63 tile A, 64..127 tile B
  // bh/XCD map unchanged: all 16 q-slots of a bh share blockIdx&7.
  // j-balance: co-resident blocks are {bi, bi+256, bi+512, bi+768}; bit8
  // alternates -> two blocks run j=v (32-v steps), two run j=15-v (17+v
  // steps) -> constant 98 tile-steps per CU (was 4*(32-v), 1.31x imbalance).
  const int bi = blockIdx.x;
  const int slot = bi >> 3;
  const int bh = (bi & 7) + 8 * (slot >> 4);
  const int v = slot & 15;
  const int j = ((bi >> 8) & 1) ? (15 - v) : v;
  const int jA = j, jB = 31 - j;
  const int tid = threadIdx.x, w = tid >> 6, lane = tid & 63, lo = lane & 15, hi = lane >> 4;
  const bf16* qp = q + (size_t)bh * 2048 * 64;
  const bf16* kp = k + (size_t)bh * 2048 * 64;
  const bf16* vtp = vt + (size_t)bh * 64 * 2048;

  {
    int rr = tid >> 4, c = (tid & 15) * 4;
    bf16x4 z;
    bf16 v1 = (rr == 0) ? (bf16)1.0f : (bf16)0.0f;
    z[0] = v1; z[1] = v1; z[2] = v1; z[3] = v1;
    *(bf16x4*)(Ones + rr * 64 + c) = z;
  }

#pragma unroll
  for (int p = 0; p < 2; ++p) {
    int u = tid + 256 * p;
    int row = u >> 3, g = (u & 7) ^ (row & 7);
    gld_lds16(kp + (size_t)row * 64 + g * 8, Ks + p * 2048 + w * 512);
    gld_lds16(vtp + (size_t)row * 2048 + g * 8, Vs + p * 2048 + w * 512);
  }

  bf16x8 qfA[2], qfB[2];
  {
    int qA = jA * 64 + w * 16 + lo;
    int qB = jB * 64 + w * 16 + lo;
    qfA[0] = *(const bf16x8*)(qp + (size_t)qA * 64 + hi * 8);
    qfA[1] = *(const bf16x8*)(qp + (size_t)qA * 64 + 32 + hi * 8);
    qfB[0] = *(const bf16x8*)(qp + (size_t)qB * 64 + hi * 8);
    qfB[1] = *(const bf16x8*)(qp + (size_t)qB * 64 + 32 + hi * 8);
  }
  f32x4 oA[4] = {}, oB[4] = {};
  f32x4 oLA = {}, oLB = {};

  VMC(0);
  BAR();

  for (int st = 0; st <= jB; ++st) {
    const int cb = (st & 1) * 4096;
    const int nb = cb ^ 4096;

    bf16x8 kf[4][2];
#pragma unroll
    for (int nt = 0; nt < 4; ++nt)
#pragma unroll
      for (int ks = 0; ks < 2; ++ks)
        kf[nt][ks] = *(const bf16x8*)(Ks + cb + (nt * 16 + lo) * 64 + ((ks * 4 + hi) ^ (lo & 7)) * 8);

    if (st < jB) {
      const int s1 = (st + 1) * 64;
#pragma unroll
      for (int p = 0; p < 2; ++p) {
        int u = tid + 256 * p;
        int row = u >> 3, g = (u & 7) ^ (row & 7);
        gld_lds16(kp + (size_t)(s1 + row) * 64 + g * 8, Ks + nb + p * 2048 + w * 512);
        gld_lds16(vtp + (size_t)row * 2048 + s1 + g * 8, Vs + nb + p * 2048 + w * 512);
      }
    }

    const bool actA = (st <= jA);
    f32x4 saccA[4] = {}, saccB[4] = {};
    __builtin_amdgcn_s_setprio(1);
    if (actA) {
#pragma unroll
      for (int nt = 0; nt < 4; ++nt)
#pragma unroll
        for (int ks = 0; ks < 2; ++ks)
          saccA[nt] = __builtin_amdgcn_mfma_f32_16x16x32_bf16(kf[nt][ks], qfA[ks], saccA[nt], 0, 0, 0);
    }
#pragma unroll
    for (int nt = 0; nt < 4; ++nt)
#pragma unroll
      for (int ks = 0; ks < 2; ++ks)
        saccB[nt] = __builtin_amdgcn_mfma_f32_16x16x32_bf16(kf[nt][ks], qfB[ks], saccB[nt], 0, 0, 0);
    __builtin_amdgcn_s_setprio(0);
    if (actA) p_store(saccA, st == jA, w, lo, hi, Ps);
    p_store(saccB, st == jB, w, lo, hi, Ps + 64 * PSTR);
    LGKM0();

    bf16x8 pfA[2], pfB[2];
#pragma unroll
    for (int ks = 0; ks < 2; ++ks) {
      pfB[ks] = *(const bf16x8*)(Ps + (64 + w * 16 + lo) * PSTR + ks * 32 + hi * 8);
      if (actA) pfA[ks] = *(const bf16x8*)(Ps + (w * 16 + lo) * PSTR + ks * 32 + hi * 8);
    }
    __builtin_amdgcn_s_setprio(1);
#pragma unroll
    for (int mt = 0; mt < 5; ++mt) {
#pragma unroll
      for (int ks = 0; ks < 2; ++ks) {
        int row = mt * 16 + lo;
        bf16x8 vf = (mt < 4)
            ? *(const bf16x8*)(Vs + cb + row * 64 + ((ks * 4 + hi) ^ (row & 7)) * 8)
            : *(const bf16x8*)(Ones + lo * 64 + ((ks * 4 + hi) ^ (lo & 7)) * 8);
        if (mt < 4) {
          oB[mt] = __builtin_amdgcn_mfma_f32_16x16x32_bf16(vf, pfB[ks], oB[mt], 0, 0, 0);
          if (actA) oA[mt] = __builtin_amdgcn_mfma_f32_16x16x32_bf16(vf, pfA[ks], oA[mt], 0, 0, 0);
        } else {
          oLB = __builtin_amdgcn_mfma_f32_16x16x32_bf16(vf, pfB[ks], oLB, 0, 0, 0);
          if (actA) oLA = __builtin_amdgcn_mfma_f32_16x16x32_bf16(vf, pfA[ks], oLA, 0, 0, 0);
        }
      }
    }
    __builtin_amdgcn_s_setprio(0);

    VMC(0);
    BAR();
  }

  const int b = bh >> 4, h = bh & 15;
  float lA = __shfl(oLA[0], lo, 64);
  float lB = __shfl(oLB[0], lo, 64);
  write_y(y, b, h, jA * 64 + w * 16 + lo, hi, oA, 1.0f / lA);
  write_y(y, b, h, jB * 64 + w * 16 + lo, hi, oB, 1.0f / lB);
}

// ---------------------------------------------------------------------------
extern "C" void kernel_launch(void* const* d_in, const int* in_sizes, int n_in,
                              void* d_out, int out_size, void* d_ws, size_t ws_size,
                              hipStream_t stream) {
  const float* x = (const float*)d_in[0];
  const float* Wqkv = (const float*)d_in[1];
  const float* Wproj = (const float*)d_in[2];
  float* out = (float*)d_out;

  const size_t YSZ = (size_t)8192 * 1024;
  char* ws = (char*)d_ws;
  bf16* xb = (bf16*)ws;      ws += (size_t)8192 * 1024 * 2;
  bf16* wqkvT = (bf16*)ws;   ws += (size_t)3072 * 1024 * 2;
  bf16* wprojT = (bf16*)ws;  ws += (size_t)1024 * 1024 * 2;
  bf16* qb = (bf16*)ws;      ws += (size_t)64 * 2048 * 64 * 2;
  bf16* kb = (bf16*)ws;      ws += (size_t)64 * 2048 * 64 * 2;
  bf16* vtb = (bf16*)ws;     ws += (size_t)64 * 2048 * 64 * 2;
  bf16* yb = (bf16*)ws;      // 88 MB total

  float* outy = out;
  float* outk = out + YSZ;
  float* outv = out + 2 * YSZ;

  k_prep<<<8192, 256, 0, stream>>>(x, xb, Wqkv, wqkvT, Wproj, wprojT);
  k_gemm_qkv<<<768, 512, 0, stream>>>(xb, wqkvT, qb, kb, vtb, outk, outv);
  k_flash<<<1024, 256, 0, stream>>>(qb, kb, vtb, yb);
  k_gemm_proj<<<256, 512, 0, stream>>>(yb, wprojT, outy);
}